// Round 6
// baseline (183.205 us; speedup 1.0000x reference)
//
#include <hip/hip_runtime.h>
#include <hip/hip_bf16.h>

#define NB 16384
#define DIN 512
#define H1 256
#define H2 128
#define NE 18
#define NT 3
#define NGH 64
#define NETOT 14

typedef float f32x4 __attribute__((ext_vector_type(4)));
typedef short s16x8 __attribute__((ext_vector_type(8)));
typedef short s16x4 __attribute__((ext_vector_type(4)));
typedef unsigned short u16;
typedef unsigned int u32;

__device__ __forceinline__ u16 f2bf(float f) {
    union { float f; u32 u; } v; v.f = f;
    u32 r = v.u + 0x7fffu + ((v.u >> 16) & 1u);
    return (u16)(r >> 16);
}
__device__ __forceinline__ float bf2f(u16 u) {
    union { u32 u; float f; } v; v.u = ((u32)u) << 16;
    return v.f;
}
// pack 2 f32 -> 2 bf16 in one u32 (low = a, high = b)
__device__ __forceinline__ u32 cvtpk(float a, float b) {
    u32 r;
    asm("v_cvt_pk_bf16_f32 %0, %1, %2" : "=v"(r) : "v"(a), "v"(b));
    return r;
}

// async global->LDS, 16B per lane. lds ptr wave-uniform; HW writes lane i at lds+16*i.
#define GLDS16(g, l) __builtin_amdgcn_global_load_lds((const u32*)(g), (u32*)(l), 16, 0, 0)
#define VMCNT0_BARRIER() do { asm volatile("s_waitcnt vmcnt(0)" ::: "memory"); __builtin_amdgcn_s_barrier(); } while (0)

// ---------------- prep: x cvt + ALL weight transposes, one launch ----------------
__global__ __launch_bounds__(256) void k_prep(
    const float* __restrict__ x, u16* __restrict__ xb,
    const float* __restrict__ sW1, const float* __restrict__ dW1, const float* __restrict__ tW1,
    const float* __restrict__ sW2, const float* __restrict__ dW2, const float* __restrict__ tW2,
    const float* __restrict__ gW1, u16* __restrict__ w1t, u16* __restrict__ w2t, u16* __restrict__ gw1t)
{
    __shared__ float lds[64 * 65];
    int bx = blockIdx.x;
    if (bx < 8192) {
        int i = (bx * 256 + threadIdx.x) * 4;
        float4 v = *reinterpret_cast<const float4*>(x + i);
        ushort4 o;
        o.x = f2bf(v.x); o.y = f2bf(v.y); o.z = f2bf(v.z); o.w = f2bf(v.w);
        *reinterpret_cast<ushort4*>(xb + i) = o;
        return;
    }
    int b = bx - 8192;
    const float* src; u16* dst; int K, N, k0, n0;
    if (b < 576) {
        int e = b >> 5, tile = b & 31;
        src = (e < 4) ? sW1 + (size_t)e * DIN * H1 : (e < 12) ? dW1 + (size_t)(e - 4) * DIN * H1
                                                              : tW1 + (size_t)(e - 12) * DIN * H1;
        dst = w1t + (size_t)e * H1 * DIN; K = DIN; N = H1;
        k0 = (tile >> 2) * 64; n0 = (tile & 3) * 64;
    } else if (b < 720) {
        int b2 = b - 576; int e = b2 >> 3, tile = b2 & 7;
        src = (e < 4) ? sW2 + (size_t)e * H1 * H2 : (e < 12) ? dW2 + (size_t)(e - 4) * H1 * H2
                                                             : tW2 + (size_t)(e - 12) * H1 * H2;
        dst = w2t + (size_t)e * H2 * H1; K = H1; N = H2;
        k0 = (tile >> 1) * 64; n0 = (tile & 1) * 64;
    } else {
        int b3 = b - 720; int t = b3 >> 3, tile = b3 & 7;
        src = gW1 + (size_t)t * DIN * NGH; dst = gw1t + (size_t)t * NGH * DIN; K = DIN; N = NGH;
        k0 = tile * 64; n0 = 0;
    }
    int t = threadIdx.x;
#pragma unroll
    for (int i = 0; i < 16; ++i) {
        int idx = i * 256 + t;
        int kk = idx >> 6, nn = idx & 63;
        lds[kk * 65 + nn] = src[(size_t)(k0 + kk) * N + n0 + nn];
    }
    __syncthreads();
#pragma unroll
    for (int i = 0; i < 16; ++i) {
        int idx = i * 256 + t;
        int nn = idx >> 6, kk = idx & 63;
        dst[(size_t)(n0 + nn) * K + k0 + kk] = f2bf(lds[kk * 65 + nn]);
    }
}

// ---------------- fused 2-layer expert kernel, 2 blocks/CU ----------------
// grid: 18 experts * 128 m-blocks (128 rows). 512 threads = 8 waves (2M x 4N), wave 64x64.
// GEMM1 swapped mfma(W1,x) -> C[n][m] with m=lane&15 -> h stored via cvt_pk + ds_write_b64.
// GEMM2: A-frags from swizzled hs LDS, B-frags (W2) straight from global; no barriers.
__global__ __launch_bounds__(512, 4) void k_expert(
    const u16* __restrict__ xb, const u16* __restrict__ w1t, const u16* __restrict__ w2t,
    const float* __restrict__ sb1, const float* __restrict__ db1, const float* __restrict__ tb1,
    const float* __restrict__ sb2, const float* __restrict__ db2, const float* __restrict__ tb2,
    u16* __restrict__ eout)
{
    // LDS: GEMM1 staging: xs[buf] @ buf*8192 (2x8KB), w1s[buf] @ 16384+buf*16384 (2x16KB) -> 48KB
    //      GEMM2: hs [128][512B] swizzled @ 0 (64KB, overlaps dead staging region)
    __shared__ __align__(128) char smem[65536];

    const int bx = blockIdx.x;
    const int e  = bx >> 7;
    const int m0 = (bx & 127) * 128;
    const int tid = threadIdx.x;
    const int w = tid >> 6, lane = tid & 63;
    const int wm = w & 1, wn = w >> 1;         // 2M x 4N
    const int l15 = lane & 15, q = lane >> 4;
    const int q16 = q * 16;
    const int swk = ((l15 >> 1) & 3) << 4;     // GEMM1 swizzle (64B rows)
    const int swh = (l15 & 7) << 4;            // hs swizzle (512B rows)

    const u16* xg  = xb + (size_t)m0 * DIN;
    const u16* w1g = w1t + (size_t)e * H1 * DIN;
    const u16* w2g = w2t + (size_t)e * H2 * H1;
    const float* b1p = (e < 4) ? sb1 + e * H1 : (e < 12) ? db1 + (e - 4) * H1 : tb1 + (e - 12) * H1;
    const float* b2p = (e < 4) ? sb2 + e * H2 : (e < 12) ? db2 + (e - 4) * H2 : tb2 + (e - 12) * H2;

    // ---- staging (per-lane inverse-swizzled global src, wave-uniform LDS dest) ----
    const int sr = lane >> 2, sc = lane & 3;
    const int soff = (sc ^ ((lane >> 3) & 3)) * 8;   // elems
    const u16* gx   = xg  + (size_t)(w * 16 + sr) * DIN + soff;
    const u16* gw1a = w1g + (size_t)(w * 32 + sr) * DIN + soff;
    const u16* gw1b = w1g + (size_t)(w * 32 + 16 + sr) * DIN + soff;
    const int lx  = w * 1024;          // + buf*8192
    const int lwa = w * 2048;          // + 16384 + buf*16384
    const int lwb = w * 2048 + 1024;

    // ---- fragment byte offsets (within current buf) ----
    int offX[4], offW[4];
#pragma unroll
    for (int mi = 0; mi < 4; ++mi)
        offX[mi] = (wm * 64 + mi * 16 + l15) * 64 + (q16 ^ swk);
#pragma unroll
    for (int nj = 0; nj < 4; ++nj)
        offW[nj] = (wn * 64 + nj * 16 + l15) * 64 + (q16 ^ swk);

    f32x4 acc1[4][4];
#pragma unroll
    for (int i = 0; i < 4; ++i)
#pragma unroll
        for (int j = 0; j < 4; ++j) acc1[i][j] = (f32x4)0.f;

    // ---- GEMM1: h[128,256] = x[128,512] @ W1t^T, 16 K-tiles of BK=32 ----
    GLDS16(gx, smem + lx);
    GLDS16(gw1a, smem + 16384 + lwa);
    GLDS16(gw1b, smem + 16384 + lwb);
    VMCNT0_BARRIER();
    for (int kt = 0; kt < 16; ++kt) {
        if (kt < 15) {
            const int nb = (kt + 1) & 1, ko = (kt + 1) * 32;
            GLDS16(gx + ko, smem + nb * 8192 + lx);
            GLDS16(gw1a + ko, smem + 16384 + nb * 16384 + lwa);
            GLDS16(gw1b + ko, smem + 16384 + nb * 16384 + lwb);
        }
        const char* xbase = smem + (kt & 1) * 8192;
        const char* wbase = smem + 16384 + (kt & 1) * 16384;
        s16x8 xf[4], wf[4];
#pragma unroll
        for (int mi = 0; mi < 4; ++mi) xf[mi] = *(const s16x8*)(xbase + offX[mi]);
#pragma unroll
        for (int nj = 0; nj < 4; ++nj) wf[nj] = *(const s16x8*)(wbase + offW[nj]);
        __builtin_amdgcn_s_setprio(1);
#pragma unroll
        for (int mi = 0; mi < 4; ++mi)
#pragma unroll
            for (int nj = 0; nj < 4; ++nj)   // SWAPPED: A=W1, B=x -> C[n][m], m=l15
                acc1[mi][nj] = __builtin_amdgcn_mfma_f32_16x16x32_bf16(wf[nj], xf[mi], acc1[mi][nj], 0, 0, 0);
        __builtin_amdgcn_s_setprio(0);
        VMCNT0_BARRIER();
    }

    // ---- h = relu(acc1 + b1) -> hs (bf16, [128][512B], swizzled), ds_write_b64 ----
#pragma unroll
    for (int mi = 0; mi < 4; ++mi) {
        const int m = wm * 64 + mi * 16 + l15;
        char* rowp = smem + m * 512;
#pragma unroll
        for (int nj = 0; nj < 4; ++nj) {
            const float4 bv = *reinterpret_cast<const float4*>(b1p + wn * 64 + nj * 16 + q * 4);
            float v0 = fmaxf(acc1[mi][nj][0] + bv.x, 0.f);
            float v1 = fmaxf(acc1[mi][nj][1] + bv.y, 0.f);
            float v2 = fmaxf(acc1[mi][nj][2] + bv.z, 0.f);
            float v3 = fmaxf(acc1[mi][nj][3] + bv.w, 0.f);
            uint2 hv; hv.x = cvtpk(v0, v1); hv.y = cvtpk(v2, v3);
            const int b = wn * 128 + nj * 32 + q * 8;   // byte offset of n0 in row
            *reinterpret_cast<uint2*>(rowp + (b ^ swh)) = hv;
        }
    }
    __syncthreads();

    // ---- GEMM2: o[128,128] = h[128,256] @ W2t^T; W2 B-frags from GLOBAL; no barriers ----
    f32x4 acc2[4][2];
#pragma unroll
    for (int i = 0; i < 4; ++i)
#pragma unroll
        for (int j = 0; j < 2; ++j) acc2[i][j] = (f32x4)0.f;
    const u16* w2p0 = w2g + (size_t)(wn * 32 + l15) * H1 + q * 8;
    const u16* w2p1 = w2g + (size_t)(wn * 32 + 16 + l15) * H1 + q * 8;
#pragma unroll
    for (int kt2 = 0; kt2 < 8; ++kt2) {
        s16x8 wf2[2], hf[4];
        wf2[0] = *(const s16x8*)(w2p0 + kt2 * 32);
        wf2[1] = *(const s16x8*)(w2p1 + kt2 * 32);
#pragma unroll
        for (int mi = 0; mi < 4; ++mi) {
            const int m = wm * 64 + mi * 16 + l15;
            hf[mi] = *(const s16x8*)(smem + m * 512 + ((kt2 * 64 + q16) ^ swh));
        }
#pragma unroll
        for (int mi = 0; mi < 4; ++mi)
#pragma unroll
            for (int pj = 0; pj < 2; ++pj)
                acc2[mi][pj] = __builtin_amdgcn_mfma_f32_16x16x32_bf16(hf[mi], wf2[pj], acc2[mi][pj], 0, 0, 0);
    }

    // ---- epilogue: relu(acc2 + b2) -> eout[e][b][h] bf16 ----
    u16* eo = eout + ((size_t)e * NB + m0) * H2;
#pragma unroll
    for (int mi = 0; mi < 4; ++mi)
#pragma unroll
        for (int pj = 0; pj < 2; ++pj) {
            const int p = wn * 32 + pj * 16 + l15;
            const float bias = b2p[p];
#pragma unroll
            for (int r = 0; r < 4; ++r) {
                const int row = wm * 64 + mi * 16 + q * 4 + r;
                float v = acc2[mi][pj][r] + bias;
                eo[(size_t)row * H2 + p] = f2bf(v > 0.f ? v : 0.f);
            }
        }
}

// ---------------- gate kernel ----------------
__global__ __launch_bounds__(256) void k_gate(
    const u16* __restrict__ xb, const u16* __restrict__ gw1t,
    const float* __restrict__ gb1, const float* __restrict__ gw2, const float* __restrict__ gb2,
    float* __restrict__ gates)
{
    __shared__ __align__(16) char smem[51200];
    u16* xs  = reinterpret_cast<u16*>(smem);
    u16* g1s = reinterpret_cast<u16*>(smem) + 4608;
    float* ghs = reinterpret_cast<float*>(smem);

    int m0 = blockIdx.x * 64;
    int tid = threadIdx.x;
    int w = tid >> 6, lane = tid & 63;
    int wm = w & 1, wn = w >> 1;
    int l15 = lane & 15, lk = (lane >> 4) * 8, lr4 = (lane >> 4) * 4;

    f32x4 acc[2][6];
#pragma unroll
    for (int i = 0; i < 2; ++i)
#pragma unroll
        for (int j = 0; j < 6; ++j) acc[i][j] = (f32x4)0.f;

    const u16* xg = xb + (size_t)m0 * DIN;
    int srow = tid >> 3, su = (tid & 7) * 8;
    for (int kc = 0; kc < DIN / 64; ++kc) {
#pragma unroll
        for (int it = 0; it < 2; ++it) {
            int rr = srow + it * 32;
            *reinterpret_cast<uint4*>(&xs[rr * 72 + su]) =
                *reinterpret_cast<const uint4*>(xg + (size_t)rr * DIN + kc * 64 + su);
        }
#pragma unroll
        for (int it = 0; it < 6; ++it) {
            int rr = srow + it * 32;
            *reinterpret_cast<uint4*>(&g1s[rr * 72 + su]) =
                *reinterpret_cast<const uint4*>(gw1t + (size_t)rr * DIN + kc * 64 + su);
        }
        __syncthreads();
        s16x8 af[2][2], bfr[6][2];
#pragma unroll
        for (int mi = 0; mi < 2; ++mi)
#pragma unroll
            for (int kk = 0; kk < 2; ++kk)
                af[mi][kk] = *reinterpret_cast<const s16x8*>(&xs[(wm * 32 + mi * 16 + l15) * 72 + kk * 32 + lk]);
#pragma unroll
        for (int nj = 0; nj < 6; ++nj)
#pragma unroll
            for (int kk = 0; kk < 2; ++kk)
                bfr[nj][kk] = *reinterpret_cast<const s16x8*>(&g1s[(wn * 96 + nj * 16 + l15) * 72 + kk * 32 + lk]);
#pragma unroll
        for (int kk = 0; kk < 2; ++kk)
#pragma unroll
            for (int mi = 0; mi < 2; ++mi)
#pragma unroll
                for (int nj = 0; nj < 6; ++nj)
                    acc[mi][nj] = __builtin_amdgcn_mfma_f32_16x16x32_bf16(af[mi][kk], bfr[nj][kk], acc[mi][nj], 0, 0, 0);
        __syncthreads();
    }
#pragma unroll
    for (int mi = 0; mi < 2; ++mi)
#pragma unroll
        for (int nj = 0; nj < 6; ++nj) {
            int col = wn * 96 + nj * 16 + l15;
            float bias = gb1[col];
#pragma unroll
            for (int r = 0; r < 4; ++r) {
                int row = wm * 32 + mi * 16 + lr4 + r;
                float v = acc[mi][nj][r] + bias;
                ghs[row * 200 + col] = v > 0.f ? v : 0.f;
            }
        }
    __syncthreads();

    if (tid < 192) {
        int tt = tid >> 6, rr = tid & 63;
        float logit[NETOT];
#pragma unroll
        for (int e2 = 0; e2 < NETOT; ++e2) logit[e2] = gb2[tt * NETOT + e2];
        const float* g2 = gw2 + tt * NGH * NETOT;
        const float* gr = &ghs[rr * 200 + tt * 64];
        for (int g = 0; g < NGH; ++g) {
            float v = gr[g];
#pragma unroll
            for (int e2 = 0; e2 < NETOT; ++e2) logit[e2] += v * g2[g * NETOT + e2];
        }
        float m = logit[0];
#pragma unroll
        for (int e2 = 1; e2 < NETOT; ++e2) m = fmaxf(m, logit[e2]);
        float s = 0.f, p[NETOT];
#pragma unroll
        for (int e2 = 0; e2 < NETOT; ++e2) { p[e2] = __expf(logit[e2] - m); s += p[e2]; }
        float inv = 1.f / s;
        float* go = gates + (size_t)(m0 + rr) * (NT * NETOT) + tt * NETOT;
#pragma unroll
        for (int e2 = 0; e2 < NETOT; ++e2) go[e2] = p[e2] * inv;
    }
}

// ---------------- combine ----------------
__global__ __launch_bounds__(256) void k_combine(
    const u16* __restrict__ eout, const float* __restrict__ gates, float* __restrict__ out)
{
    int tid = threadIdx.x;
    int lr = tid >> 5, hq = tid & 31;
    int b = blockIdx.x * 8 + lr;
    int h0 = hq * 4;
    const float* g = gates + (size_t)b * (NT * NETOT);
    float o0[4] = {0, 0, 0, 0}, o1[4] = {0, 0, 0, 0}, o2[4] = {0, 0, 0, 0};
#pragma unroll
    for (int e = 0; e < NE; ++e) {
        ushort4 ev = *reinterpret_cast<const ushort4*>(&eout[((size_t)e * NB + b) * H2 + h0]);
        float v0 = bf2f(ev.x), v1 = bf2f(ev.y), v2 = bf2f(ev.z), v3 = bf2f(ev.w);
        if (e < 12) {
            float wa = g[e], wb = g[NETOT + e], wc = g[2 * NETOT + e];
            o0[0] += wa * v0; o0[1] += wa * v1; o0[2] += wa * v2; o0[3] += wa * v3;
            o1[0] += wb * v0; o1[1] += wb * v1; o1[2] += wb * v2; o1[3] += wb * v3;
            o2[0] += wc * v0; o2[1] += wc * v1; o2[2] += wc * v2; o2[3] += wc * v3;
        } else {
            int t = (e - 12) >> 1, te = (e - 12) & 1;
            float wt = g[t * NETOT + 12 + te];
            float* ot = (t == 0) ? o0 : (t == 1) ? o1 : o2;
            ot[0] += wt * v0; ot[1] += wt * v1; ot[2] += wt * v2; ot[3] += wt * v3;
        }
    }
    size_t base = (size_t)b * H2 + h0;
    *reinterpret_cast<float4*>(&out[0 * (size_t)NB * H2 + base]) = make_float4(o0[0], o0[1], o0[2], o0[3]);
    *reinterpret_cast<float4*>(&out[1 * (size_t)NB * H2 + base]) = make_float4(o1[0], o1[1], o1[2], o1[3]);
    *reinterpret_cast<float4*>(&out[2 * (size_t)NB * H2 + base]) = make_float4(o2[0], o2[1], o2[2], o2[3]);
}

extern "C" void kernel_launch(void* const* d_in, const int* in_sizes, int n_in,
                              void* d_out, int out_size, void* d_ws, size_t ws_size,
                              hipStream_t stream)
{
    const float* x   = (const float*)d_in[0];
    const float* sW1 = (const float*)d_in[2];
    const float* sb1 = (const float*)d_in[3];
    const float* sW2 = (const float*)d_in[4];
    const float* sb2 = (const float*)d_in[5];
    const float* dW1 = (const float*)d_in[6];
    const float* db1 = (const float*)d_in[7];
    const float* dW2 = (const float*)d_in[8];
    const float* db2 = (const float*)d_in[9];
    const float* tW1 = (const float*)d_in[10];
    const float* tb1 = (const float*)d_in[11];
    const float* tW2 = (const float*)d_in[12];
    const float* tb2 = (const float*)d_in[13];
    const float* gW1 = (const float*)d_in[14];
    const float* gb1 = (const float*)d_in[15];
    const float* gW2 = (const float*)d_in[16];
    const float* gb2 = (const float*)d_in[17];

    char* ws = (char*)d_ws;
    u16*  xb    = (u16*)(ws + 0);
    u16*  w1t   = (u16*)(ws + 16777216);
    u16*  w2t   = (u16*)(ws + 21495808);
    u16*  gw1t  = (u16*)(ws + 22675456);
    float* gates = (float*)(ws + 22872064);
    u16*  eout  = (u16*)(ws + 25624576);

    k_prep<<<dim3(8936), dim3(256), 0, stream>>>(x, xb, sW1, dW1, tW1, sW2, dW2, tW2, gW1, w1t, w2t, gw1t);
    k_gate<<<dim3(NB / 64), dim3(256), 0, stream>>>(xb, gw1t, gb1, gW2, gb2, gates);
    k_expert<<<dim3(NE * (NB / 128)), dim3(512), 0, stream>>>(xb, w1t, w2t, sb1, db1, tb1, sb2, db2, tb2, eout);
    k_combine<<<dim3(NB / 8), dim3(256), 0, stream>>>(eout, gates, (float*)d_out);
}

// Round 7
// 148.114 us; speedup vs baseline: 1.2369x; 1.2369x over previous
//
#include <hip/hip_runtime.h>
#include <hip/hip_bf16.h>

#define NB 16384
#define DIN 512
#define H1 256
#define H2 128
#define NE 18
#define NT 3
#define NGH 64
#define NETOT 14

typedef float f32x4 __attribute__((ext_vector_type(4)));
typedef short s16x8 __attribute__((ext_vector_type(8)));
typedef unsigned short u16;
typedef unsigned int u32;

__device__ __forceinline__ u16 f2bf(float f) {
    union { float f; u32 u; } v; v.f = f;
    u32 r = v.u + 0x7fffu + ((v.u >> 16) & 1u);
    return (u16)(r >> 16);
}
__device__ __forceinline__ float bf2f(u16 u) {
    union { u32 u; float f; } v; v.u = ((u32)u) << 16;
    return v.f;
}
__device__ __forceinline__ u32 cvtpk(float a, float b) {
    u32 r;
    asm("v_cvt_pk_bf16_f32 %0, %1, %2" : "=v"(r) : "v"(a), "v"(b));
    return r;
}

#define GLDS16(g, l) __builtin_amdgcn_global_load_lds((const u32*)(g), (u32*)(l), 16, 0, 0)

// ---------------- prep: x cvt + ALL weight transposes, one launch ----------------
__global__ __launch_bounds__(256) void k_prep(
    const float* __restrict__ x, u16* __restrict__ xb,
    const float* __restrict__ sW1, const float* __restrict__ dW1, const float* __restrict__ tW1,
    const float* __restrict__ sW2, const float* __restrict__ dW2, const float* __restrict__ tW2,
    const float* __restrict__ gW1, u16* __restrict__ w1t, u16* __restrict__ w2t, u16* __restrict__ gw1t)
{
    __shared__ float lds[64 * 65];
    int bx = blockIdx.x;
    if (bx < 8192) {
        int i = (bx * 256 + threadIdx.x) * 4;
        float4 v = *reinterpret_cast<const float4*>(x + i);
        ushort4 o;
        o.x = f2bf(v.x); o.y = f2bf(v.y); o.z = f2bf(v.z); o.w = f2bf(v.w);
        *reinterpret_cast<ushort4*>(xb + i) = o;
        return;
    }
    int b = bx - 8192;
    const float* src; u16* dst; int K, N, k0, n0;
    if (b < 576) {
        int e = b >> 5, tile = b & 31;
        src = (e < 4) ? sW1 + (size_t)e * DIN * H1 : (e < 12) ? dW1 + (size_t)(e - 4) * DIN * H1
                                                              : tW1 + (size_t)(e - 12) * DIN * H1;
        dst = w1t + (size_t)e * H1 * DIN; K = DIN; N = H1;
        k0 = (tile >> 2) * 64; n0 = (tile & 3) * 64;
    } else if (b < 720) {
        int b2 = b - 576; int e = b2 >> 3, tile = b2 & 7;
        src = (e < 4) ? sW2 + (size_t)e * H1 * H2 : (e < 12) ? dW2 + (size_t)(e - 4) * H1 * H2
                                                             : tW2 + (size_t)(e - 12) * H1 * H2;
        dst = w2t + (size_t)e * H2 * H1; K = H1; N = H2;
        k0 = (tile >> 1) * 64; n0 = (tile & 1) * 64;
    } else {
        int b3 = b - 720; int t = b3 >> 3, tile = b3 & 7;
        src = gW1 + (size_t)t * DIN * NGH; dst = gw1t + (size_t)t * NGH * DIN; K = DIN; N = NGH;
        k0 = tile * 64; n0 = 0;
    }
    int t = threadIdx.x;
#pragma unroll
    for (int i = 0; i < 16; ++i) {
        int idx = i * 256 + t;
        int kk = idx >> 6, nn = idx & 63;
        lds[kk * 65 + nn] = src[(size_t)(k0 + kk) * N + n0 + nn];
    }
    __syncthreads();
#pragma unroll
    for (int i = 0; i < 16; ++i) {
        int idx = i * 256 + t;
        int nn = idx >> 6, kk = idx & 63;
        dst[(size_t)(n0 + nn) * K + k0 + kk] = f2bf(lds[kk * 65 + nn]);
    }
}

// ---------------- fused expert (+gate) kernel ----------------
// blocks [0,2304): experts. 256 threads = 4 waves (1M x 4N), wave tile 128x64.
//   BM=128, BN=256, BK=32, double-buffered staging with COUNTED vmcnt(6) wait
//   (no drain-0 in main loop). GEMM2: h from padded LDS, W2 from global, no barriers.
// blocks [2304,2560): gate path (independent work, fills the expert tail).
__global__ __launch_bounds__(256, 2) void k_expert_gate(
    const u16* __restrict__ xb, const u16* __restrict__ w1t, const u16* __restrict__ w2t,
    const float* __restrict__ sb1, const float* __restrict__ db1, const float* __restrict__ tb1,
    const float* __restrict__ sb2, const float* __restrict__ db2, const float* __restrict__ tb2,
    u16* __restrict__ eout,
    const u16* __restrict__ gw1t, const float* __restrict__ gb1,
    const float* __restrict__ gw2, const float* __restrict__ gb2, float* __restrict__ gates)
{
    // expert LDS: staging buf c @ c*24576: xs [0,8K), w1s [8K,24K)  (48KB total)
    //             GEMM2: hs [128][528B] @ 0 (67584 B, overlays staging)
    __shared__ __align__(128) char smem[67584];

    const int bid = blockIdx.x;
    const int tid = threadIdx.x;

    if (bid >= 2304) {
        // ================= GATE PATH =================
        u16* xs  = reinterpret_cast<u16*>(smem);
        u16* g1s = reinterpret_cast<u16*>(smem) + 4608;
        float* ghs = reinterpret_cast<float*>(smem);

        int m0 = (bid - 2304) * 64;
        int w = tid >> 6, lane = tid & 63;
        int wm = w & 1, wn = w >> 1;
        int l15 = lane & 15, lk = (lane >> 4) * 8, lr4 = (lane >> 4) * 4;

        f32x4 acc[2][6];
#pragma unroll
        for (int i = 0; i < 2; ++i)
#pragma unroll
            for (int j = 0; j < 6; ++j) acc[i][j] = (f32x4)0.f;

        const u16* xg = xb + (size_t)m0 * DIN;
        int srow = tid >> 3, su = (tid & 7) * 8;
        for (int kc = 0; kc < DIN / 64; ++kc) {
#pragma unroll
            for (int it = 0; it < 2; ++it) {
                int rr = srow + it * 32;
                *reinterpret_cast<uint4*>(&xs[rr * 72 + su]) =
                    *reinterpret_cast<const uint4*>(xg + (size_t)rr * DIN + kc * 64 + su);
            }
#pragma unroll
            for (int it = 0; it < 6; ++it) {
                int rr = srow + it * 32;
                *reinterpret_cast<uint4*>(&g1s[rr * 72 + su]) =
                    *reinterpret_cast<const uint4*>(gw1t + (size_t)rr * DIN + kc * 64 + su);
            }
            __syncthreads();
            s16x8 af[2][2], bfr[6][2];
#pragma unroll
            for (int mi = 0; mi < 2; ++mi)
#pragma unroll
                for (int kk = 0; kk < 2; ++kk)
                    af[mi][kk] = *reinterpret_cast<const s16x8*>(&xs[(wm * 32 + mi * 16 + l15) * 72 + kk * 32 + lk]);
#pragma unroll
            for (int nj = 0; nj < 6; ++nj)
#pragma unroll
                for (int kk = 0; kk < 2; ++kk)
                    bfr[nj][kk] = *reinterpret_cast<const s16x8*>(&g1s[(wn * 96 + nj * 16 + l15) * 72 + kk * 32 + lk]);
#pragma unroll
            for (int kk = 0; kk < 2; ++kk)
#pragma unroll
                for (int mi = 0; mi < 2; ++mi)
#pragma unroll
                    for (int nj = 0; nj < 6; ++nj)
                        acc[mi][nj] = __builtin_amdgcn_mfma_f32_16x16x32_bf16(af[mi][kk], bfr[nj][kk], acc[mi][nj], 0, 0, 0);
            __syncthreads();
        }
#pragma unroll
        for (int mi = 0; mi < 2; ++mi)
#pragma unroll
            for (int nj = 0; nj < 6; ++nj) {
                int col = wn * 96 + nj * 16 + l15;
                float bias = gb1[col];
#pragma unroll
                for (int r = 0; r < 4; ++r) {
                    int row = wm * 32 + mi * 16 + lr4 + r;
                    float v = acc[mi][nj][r] + bias;
                    ghs[row * 200 + col] = v > 0.f ? v : 0.f;
                }
            }
        __syncthreads();

        if (tid < 192) {
            int tt = tid >> 6, rr = tid & 63;
            float logit[NETOT];
#pragma unroll
            for (int e2 = 0; e2 < NETOT; ++e2) logit[e2] = gb2[tt * NETOT + e2];
            const float* g2 = gw2 + tt * NGH * NETOT;
            const float* gr = &ghs[rr * 200 + tt * 64];
            for (int g = 0; g < NGH; ++g) {
                float v = gr[g];
#pragma unroll
                for (int e2 = 0; e2 < NETOT; ++e2) logit[e2] += v * g2[g * NETOT + e2];
            }
            float m = logit[0];
#pragma unroll
            for (int e2 = 1; e2 < NETOT; ++e2) m = fmaxf(m, logit[e2]);
            float s = 0.f, p[NETOT];
#pragma unroll
            for (int e2 = 0; e2 < NETOT; ++e2) { p[e2] = __expf(logit[e2] - m); s += p[e2]; }
            float inv = 1.f / s;
            float* go = gates + (size_t)(m0 + rr) * (NT * NETOT) + tt * NETOT;
#pragma unroll
            for (int e2 = 0; e2 < NETOT; ++e2) go[e2] = p[e2] * inv;
        }
        return;
    }

    // ================= EXPERT PATH =================
    const int e  = bid >> 7;
    const int m0 = (bid & 127) * 128;
    const int w = tid >> 6, lane = tid & 63;     // 4 waves, wn = w
    const int l15 = lane & 15, q = lane >> 4;
    const int q16 = q * 16;
    const int swk = ((l15 >> 1) & 3) << 4;       // BK=32 row (64B) swizzle

    const u16* xg  = xb + (size_t)m0 * DIN;
    const u16* w1g = w1t + (size_t)e * H1 * DIN;
    const u16* w2g = w2t + (size_t)e * H2 * H1;
    const float* b1p = (e < 4) ? sb1 + e * H1 : (e < 12) ? db1 + (e - 4) * H1 : tb1 + (e - 12) * H1;
    const float* b2p = (e < 4) ? sb2 + e * H2 : (e < 12) ? db2 + (e - 4) * H2 : tb2 + (e - 12) * H2;

    // staging: per-lane inverse-swizzled global src, wave-uniform LDS dest
    const int sr = lane >> 2, sc = lane & 3;
    const u16* gx[2]; int lx[2];
#pragma unroll
    for (int j = 0; j < 2; ++j) {
        int row = w * 32 + j * 16 + sr;
        gx[j] = xg + (size_t)row * DIN + ((sc ^ ((row >> 1) & 3)) * 8);
        lx[j] = w * 2048 + j * 1024;           // + buf*24576
    }
    const u16* gw1[4]; int lw1[4];
#pragma unroll
    for (int j = 0; j < 4; ++j) {
        int row = w * 64 + j * 16 + sr;
        gw1[j] = w1g + (size_t)row * DIN + ((sc ^ ((row >> 1) & 3)) * 8);
        lw1[j] = 8192 + w * 4096 + j * 1024;   // + buf*24576
    }

    // fragment offsets within current buf
    int offX[8], offW[4];
#pragma unroll
    for (int mi = 0; mi < 8; ++mi)
        offX[mi] = (mi * 16 + l15) * 64 + (q16 ^ swk);
#pragma unroll
    for (int nj = 0; nj < 4; ++nj)
        offW[nj] = 8192 + (w * 64 + nj * 16 + l15) * 64 + (q16 ^ swk);

    f32x4 acc1[8][4];
#pragma unroll
    for (int i = 0; i < 8; ++i)
#pragma unroll
        for (int j = 0; j < 4; ++j) acc1[i][j] = (f32x4)0.f;

    // ---- GEMM1: h[128,256] = x[128,512] @ W1t^T, 16 K-tiles BK=32, counted-wait dbuf ----
#pragma unroll
    for (int j = 0; j < 2; ++j) GLDS16(gx[j], smem + lx[j]);
#pragma unroll
    for (int j = 0; j < 4; ++j) GLDS16(gw1[j], smem + lw1[j]);

    for (int kt = 0; kt < 16; ++kt) {
        if (kt < 15) {
            const int nb = ((kt + 1) & 1) * 24576, ko = (kt + 1) * 32;
#pragma unroll
            for (int j = 0; j < 2; ++j) GLDS16(gx[j] + ko, smem + nb + lx[j]);
#pragma unroll
            for (int j = 0; j < 4; ++j) GLDS16(gw1[j] + ko, smem + nb + lw1[j]);
            asm volatile("s_waitcnt vmcnt(6)" ::: "memory");   // tile-kt loads done; 6 newest stay in flight
        } else {
            asm volatile("s_waitcnt vmcnt(0)" ::: "memory");
        }
        __builtin_amdgcn_s_barrier();                           // everyone's tile-kt data in LDS

        const char* cb = smem + (kt & 1) * 24576;
        s16x8 xf[8], wf[4];
#pragma unroll
        for (int nj = 0; nj < 4; ++nj) wf[nj] = *(const s16x8*)(cb + offW[nj]);
#pragma unroll
        for (int mi = 0; mi < 8; ++mi) xf[mi] = *(const s16x8*)(cb + offX[mi]);
        __builtin_amdgcn_s_setprio(1);
#pragma unroll
        for (int mi = 0; mi < 8; ++mi)
#pragma unroll
            for (int nj = 0; nj < 4; ++nj)   // SWAPPED: A=W1, B=x -> C col = m (l15), row = n (q*4+r)
                acc1[mi][nj] = __builtin_amdgcn_mfma_f32_16x16x32_bf16(wf[nj], xf[mi], acc1[mi][nj], 0, 0, 0);
        __builtin_amdgcn_s_setprio(0);
        asm volatile("s_waitcnt lgkmcnt(0)" ::: "memory");      // our ds_reads done
        __builtin_amdgcn_s_barrier();                           // safe to overwrite this buf next iter
    }

    // ---- h = relu(acc1 + b1) -> hs [128 rows][528 B] (padded rows, no swizzle) ----
#pragma unroll
    for (int mi = 0; mi < 8; ++mi) {
        const int m = mi * 16 + l15;
        char* rowp = smem + m * 528;
#pragma unroll
        for (int nj = 0; nj < 4; ++nj) {
            const int n0 = w * 64 + nj * 16 + q * 4;
            const float4 bv = *reinterpret_cast<const float4*>(b1p + n0);
            float v0 = fmaxf(acc1[mi][nj][0] + bv.x, 0.f);
            float v1 = fmaxf(acc1[mi][nj][1] + bv.y, 0.f);
            float v2 = fmaxf(acc1[mi][nj][2] + bv.z, 0.f);
            float v3 = fmaxf(acc1[mi][nj][3] + bv.w, 0.f);
            uint2 hv; hv.x = cvtpk(v0, v1); hv.y = cvtpk(v2, v3);
            *reinterpret_cast<uint2*>(rowp + n0 * 2) = hv;
        }
    }
    __syncthreads();

    // ---- GEMM2: o[128,128] = h[128,256] @ W2t^T; W2 from global; no barriers ----
    f32x4 acc2[8][2];
#pragma unroll
    for (int i = 0; i < 8; ++i)
#pragma unroll
        for (int j = 0; j < 2; ++j) acc2[i][j] = (f32x4)0.f;
    const u16* w2p0 = w2g + (size_t)(w * 32 + l15) * H1 + q * 8;
    const u16* w2p1 = w2g + (size_t)(w * 32 + 16 + l15) * H1 + q * 8;
#pragma unroll
    for (int kt2 = 0; kt2 < 8; ++kt2) {
        s16x8 wf2[2], hf[8];
        wf2[0] = *(const s16x8*)(w2p0 + kt2 * 32);
        wf2[1] = *(const s16x8*)(w2p1 + kt2 * 32);
#pragma unroll
        for (int mi = 0; mi < 8; ++mi)
            hf[mi] = *(const s16x8*)(smem + (mi * 16 + l15) * 528 + kt2 * 64 + q16);
#pragma unroll
        for (int mi = 0; mi < 8; ++mi)
#pragma unroll
            for (int pj = 0; pj < 2; ++pj)
                acc2[mi][pj] = __builtin_amdgcn_mfma_f32_16x16x32_bf16(hf[mi], wf2[pj], acc2[mi][pj], 0, 0, 0);
    }

    // ---- epilogue: relu(acc2 + b2) -> eout[e][b][h] bf16 ----
    u16* eo = eout + ((size_t)e * NB + m0) * H2;
#pragma unroll
    for (int mi = 0; mi < 8; ++mi)
#pragma unroll
        for (int pj = 0; pj < 2; ++pj) {
            const int p = w * 32 + pj * 16 + l15;
            const float bias = b2p[p];
#pragma unroll
            for (int r = 0; r < 4; ++r) {
                const int row = mi * 16 + q * 4 + r;
                float v = acc2[mi][pj][r] + bias;
                eo[(size_t)row * H2 + p] = f2bf(v > 0.f ? v : 0.f);
            }
        }
}

// ---------------- combine ----------------
__global__ __launch_bounds__(256) void k_combine(
    const u16* __restrict__ eout, const float* __restrict__ gates, float* __restrict__ out)
{
    int tid = threadIdx.x;
    int lr = tid >> 5, hq = tid & 31;
    int b = blockIdx.x * 8 + lr;
    int h0 = hq * 4;
    const float* g = gates + (size_t)b * (NT * NETOT);
    float o0[4] = {0, 0, 0, 0}, o1[4] = {0, 0, 0, 0}, o2[4] = {0, 0, 0, 0};
#pragma unroll
    for (int e = 0; e < NE; ++e) {
        ushort4 ev = *reinterpret_cast<const ushort4*>(&eout[((size_t)e * NB + b) * H2 + h0]);
        float v0 = bf2f(ev.x), v1 = bf2f(ev.y), v2 = bf2f(ev.z), v3 = bf2f(ev.w);
        if (e < 12) {
            float wa = g[e], wb = g[NETOT + e], wc = g[2 * NETOT + e];
            o0[0] += wa * v0; o0[1] += wa * v1; o0[2] += wa * v2; o0[3] += wa * v3;
            o1[0] += wb * v0; o1[1] += wb * v1; o1[2] += wb * v2; o1[3] += wb * v3;
            o2[0] += wc * v0; o2[1] += wc * v1; o2[2] += wc * v2; o2[3] += wc * v3;
        } else {
            int t = (e - 12) >> 1, te = (e - 12) & 1;
            float wt = g[t * NETOT + 12 + te];
            float* ot = (t == 0) ? o0 : (t == 1) ? o1 : o2;
            ot[0] += wt * v0; ot[1] += wt * v1; ot[2] += wt * v2; ot[3] += wt * v3;
        }
    }
    size_t base = (size_t)b * H2 + h0;
    *reinterpret_cast<float4*>(&out[0 * (size_t)NB * H2 + base]) = make_float4(o0[0], o0[1], o0[2], o0[3]);
    *reinterpret_cast<float4*>(&out[1 * (size_t)NB * H2 + base]) = make_float4(o1[0], o1[1], o1[2], o1[3]);
    *reinterpret_cast<float4*>(&out[2 * (size_t)NB * H2 + base]) = make_float4(o2[0], o2[1], o2[2], o2[3]);
}

extern "C" void kernel_launch(void* const* d_in, const int* in_sizes, int n_in,
                              void* d_out, int out_size, void* d_ws, size_t ws_size,
                              hipStream_t stream)
{
    const float* x   = (const float*)d_in[0];
    const float* sW1 = (const float*)d_in[2];
    const float* sb1 = (const float*)d_in[3];
    const float* sW2 = (const float*)d_in[4];
    const float* sb2 = (const float*)d_in[5];
    const float* dW1 = (const float*)d_in[6];
    const float* db1 = (const float*)d_in[7];
    const float* dW2 = (const float*)d_in[8];
    const float* db2 = (const float*)d_in[9];
    const float* tW1 = (const float*)d_in[10];
    const float* tb1 = (const float*)d_in[11];
    const float* tW2 = (const float*)d_in[12];
    const float* tb2 = (const float*)d_in[13];
    const float* gW1 = (const float*)d_in[14];
    const float* gb1 = (const float*)d_in[15];
    const float* gW2 = (const float*)d_in[16];
    const float* gb2 = (const float*)d_in[17];

    char* ws = (char*)d_ws;
    u16*  xb    = (u16*)(ws + 0);
    u16*  w1t   = (u16*)(ws + 16777216);
    u16*  w2t   = (u16*)(ws + 21495808);
    u16*  gw1t  = (u16*)(ws + 22675456);
    float* gates = (float*)(ws + 22872064);
    u16*  eout  = (u16*)(ws + 25624576);

    k_prep<<<dim3(8936), dim3(256), 0, stream>>>(x, xb, sW1, dW1, tW1, sW2, dW2, tW2, gW1, w1t, w2t, gw1t);
    k_expert_gate<<<dim3(2560), dim3(256), 0, stream>>>(xb, w1t, w2t, sb1, db1, tb1, sb2, db2, tb2,
                                                        eout, gw1t, gb1, gW2, gb2, gates);
    k_combine<<<dim3(NB / 8), dim3(256), 0, stream>>>(eout, gates, (float*)d_out);
}